// Round 1
// baseline (6590.195 us; speedup 1.0000x reference)
//
#include <hip/hip_runtime.h>
#include <hip/hip_bf16.h>

#define Nn 512
#define NNn (512*512)
#define NP1 513
#define Dd 512
#define Hh 16
#define KK 128
#define MMm 8
#define LLl 4
#define Ee 2048
#define HD 8192
#define ATTN_LD 516
#define SCALING 0.17677669529663687f
#define PSI_LD 132

__device__ __forceinline__ float gelu_f(float v){
    return 0.5f * v * (1.f + erff(v * 0.70710678118654752f));
}

// ---------------- preprocessing ----------------

__global__ void k_scatter(const int* __restrict__ ei, int* sc1, int* sc2){
    int e = blockIdx.x * 256 + threadIdx.x;
    if (e >= Ee) return;
    int f = ei[e], t = ei[Ee + e];
    atomicMax(&sc1[f * Nn + t], e + 1);
    atomicMax(&sc2[t * Nn + f], e + 1);
}

__global__ __launch_bounds__(256) void k_combine(const int* __restrict__ sc1, const int* __restrict__ sc2,
                          const int* __restrict__ eat, int* __restrict__ edge_types, int* __restrict__ degrees){
    int i = blockIdx.x, tid = threadIdx.x;
    int cnt = 0;
    for (int it = 0; it < 2; it++){
        int j = tid + it * 256;
        int v2 = sc2[i * Nn + j], v1 = sc1[i * Nn + j];
        int et = v2 ? eat[v2 - 1] : (v1 ? eat[v1 - 1] : 0);
        edge_types[i * Nn + j] = et;
        cnt += (et != 0);
    }
    __shared__ int red[256];
    red[tid] = cnt; __syncthreads();
    for (int s = 128; s > 0; s >>= 1){ if (tid < s) red[tid] += red[tid + s]; __syncthreads(); }
    if (tid == 0) degrees[i] = red[0];
}

__global__ void k_dist(const float* __restrict__ pos, float* __restrict__ dist){
    int p = blockIdx.x * 256 + threadIdx.x;
    int i = p >> 9, j = p & 511;
    float dx = pos[i*3+0] - pos[j*3+0];
    float dy = pos[i*3+1] - pos[j*3+1];
    float dz = pos[i*3+2] - pos[j*3+2];
    dist[p] = sqrtf(dx*dx + dy*dy + dz*dz + 1e-12f);
}

// bias = phi_spd + phi_edge  (phi_3d added later by k_psi)
__global__ __launch_bounds__(256) void k_bias_init(const int* __restrict__ spatial_pos, const int* __restrict__ edge_input,
                            const float* __restrict__ spd_tab, const float* __restrict__ edge_tab,
                            const float* __restrict__ edge_dis, float* __restrict__ bias){
    __shared__ float etab[512];
    __shared__ float ewL[2048];
    int tid = threadIdx.x;
    etab[tid] = edge_tab[tid];
    etab[tid + 256] = edge_tab[tid + 256];
    for (int it = 0; it < 8; it++) ewL[tid + it * 256] = edge_dis[tid + it * 256];
    __syncthreads();
    int pp = tid >> 4, ho = tid & 15;
    int pair = blockIdx.x * 16 + pp;
    int sp = spatial_pos[pair];
    const int* eiv = edge_input + (long long)pair * 8;
    float acc = 0.f;
    #pragma unroll
    for (int m = 0; m < MMm; m++){
        int bt = eiv[m];
        const float* er = &etab[bt * 16];
        const float* wr = &ewL[m * 256 + ho];
        #pragma unroll
        for (int hi = 0; hi < 16; hi++) acc += er[hi] * wr[hi * 16];
    }
    float spv = (sp == 0) ? 1.f : (float)sp;
    bias[(long long)ho * NNn + pair] = spd_tab[sp * 16 + ho] + acc / spv;
}

// fused: psi [64 pairs x 128] in LDS -> sumpsi accumulation, h=gelu(psi@pW1^T), phi=h@pW2^T added to bias
__global__ __launch_bounds__(256) void k_psi(const float* __restrict__ dist, const int* __restrict__ edge_types,
                     const float* __restrict__ gamma_tab, const float* __restrict__ beta_tab,
                     const float* __restrict__ means, const float* __restrict__ stds,
                     const float* __restrict__ pW1, const float* __restrict__ pW2,
                     float* __restrict__ sumpsi, float* __restrict__ bias){
    __shared__ float psiL[64 * PSI_LD];
    __shared__ float mn[128], isd[128], nc[128], xgL[64];
    int tid = threadIdx.x;
    int i = blockIdx.y, jc = blockIdx.x;
    if (tid < 128){
        float s = fabsf(stds[tid]) + 0.01f;
        mn[tid] = means[tid];
        isd[tid] = 1.f / s;
        nc[tid] = 0.3989422804014327f / s;
    }
    if (tid < 64){
        int j = jc * 64 + tid;
        int et = edge_types[i * Nn + j];
        xgL[tid] = gamma_tab[et] * dist[i * Nn + j] + beta_tab[et];
    }
    __syncthreads();
    for (int it = 0; it < 32; it++){
        int v = tid + it * 256;
        int k = v & 127, p = v >> 7;
        float t = (xgL[p] - mn[k]) * isd[k];
        psiL[p * PSI_LD + k] = nc[k] * expf(-0.5f * t * t);
    }
    __syncthreads();
    if (tid < 128){
        float a = 0.f;
        for (int p = 0; p < 64; p++) a += psiL[p * PSI_LD + tid];
        atomicAdd(&sumpsi[i * KK + tid], a);
    }
    int p = tid >> 2, to = tid & 3;
    const float4* psirow = (const float4*)&psiL[p * PSI_LD];
    float hv[32];
    for (int og = 0; og < 32; og++){
        int o = to * 32 + og;
        const float4* w = (const float4*)(pW1 + o * 128);
        float a = 0.f;
        #pragma unroll
        for (int k4 = 0; k4 < 32; k4++){
            float4 ps = psirow[k4]; float4 ww = w[k4];
            a += ps.x*ww.x + ps.y*ww.y + ps.z*ww.z + ps.w*ww.w;
        }
        hv[og] = gelu_f(a);
    }
    float ph[16];
    #pragma unroll
    for (int hh = 0; hh < 16; hh++) ph[hh] = 0.f;
    for (int og = 0; og < 32; og++){
        float v = hv[og];
        int o = to * 32 + og;
        #pragma unroll
        for (int hh = 0; hh < 16; hh++) ph[hh] += v * pW2[hh * 128 + o];
    }
    #pragma unroll
    for (int hh = 0; hh < 16; hh++){
        float v = ph[hh];
        v += __shfl_xor(v, 1);
        v += __shfl_xor(v, 2);
        ph[hh] = v;
    }
    if (to == 0){
        int j = jc * 64 + p;
        #pragma unroll
        for (int hh = 0; hh < 16; hh++)
            bias[(long long)hh * NNn + i * Nn + j] += ph[hh];
    }
}

__global__ __launch_bounds__(256) void k_xinit(const float* __restrict__ atoms_x, const float* __restrict__ atom_tab,
                        const float* __restrict__ degree_tab, const float* __restrict__ w3d,
                        const float* __restrict__ sumpsi, const int* __restrict__ atoms,
                        const int* __restrict__ degrees, const float* __restrict__ cls_token,
                        float* __restrict__ x){
    int b = blockIdx.x, tid = threadIdx.x;
    if (b == 0){
        x[tid] = cls_token[tid];
        x[tid + 256] = cls_token[tid + 256];
        return;
    }
    int i = b - 1;
    __shared__ float spv[128];
    if (tid < 128) spv[tid] = sumpsi[i * KK + tid];
    __syncthreads();
    int a = atoms[i], dg = degrees[i];
    for (int it = 0; it < 2; it++){
        int d = tid + it * 256;
        float v = atoms_x[i * Dd + d] + atom_tab[a * Dd + d] + degree_tab[dg * Dd + d];
        const float4* w = (const float4*)(w3d + d * KK);
        float s = 0.f;
        #pragma unroll
        for (int k4 = 0; k4 < 32; k4++){
            float4 ww = w[k4];
            s += spv[k4*4+0]*ww.x + spv[k4*4+1]*ww.y + spv[k4*4+2]*ww.z + spv[k4*4+3]*ww.w;
        }
        x[(i + 1) * Dd + d] = v + s;
    }
}

// ---------------- GEMM: TB=1 -> C=A@B^T (B[N,K]); TB=0 -> C=A@B (B[K,N]) ----------------
template<int TB>
__global__ __launch_bounds__(256) void k_gemm(const float* __restrict__ A, const float* __restrict__ B,
                       float* __restrict__ C, int Mr, int Nc, int Ka,
                       int lda, int ldb, int ldc,
                       long long sAz, long long sBz, long long sCz){
    A += (long long)blockIdx.z * sAz;
    B += (long long)blockIdx.z * sBz;
    C += (long long)blockIdx.z * sCz;
    __shared__ __align__(16) float As[16][68];
    __shared__ __align__(16) float Bs[16][68];
    int tid = threadIdx.x;
    int tx = tid & 15, ty = tid >> 4;
    int row0 = blockIdx.y * 64, col0 = blockIdx.x * 64;
    int lr = tid >> 2, lk = (tid & 3) * 4;
    float acc[4][4] = {};
    for (int k0 = 0; k0 < Ka; k0 += 16){
        // A tile (k-major store)
        {
            int r = row0 + lr;
            float4 a = make_float4(0.f, 0.f, 0.f, 0.f);
            if (r < Mr){
                const float* ap = A + (long long)r * lda + k0 + lk;
                int rem = Ka - (k0 + lk);
                if (rem >= 4) a = *(const float4*)ap;
                else if (rem > 0){ a.x = ap[0]; if (rem > 1) a.y = ap[1]; if (rem > 2) a.z = ap[2]; }
            }
            As[lk+0][lr] = a.x; As[lk+1][lr] = a.y; As[lk+2][lr] = a.z; As[lk+3][lr] = a.w;
        }
        if (TB){
            int c = col0 + lr;
            float4 b = make_float4(0.f, 0.f, 0.f, 0.f);
            if (c < Nc){
                const float* bp = B + (long long)c * ldb + k0 + lk;
                int rem = Ka - (k0 + lk);
                if (rem >= 4) b = *(const float4*)bp;
                else if (rem > 0){ b.x = bp[0]; if (rem > 1) b.y = bp[1]; if (rem > 2) b.z = bp[2]; }
            }
            Bs[lk+0][lr] = b.x; Bs[lk+1][lr] = b.y; Bs[lk+2][lr] = b.z; Bs[lk+3][lr] = b.w;
        } else {
            int bk = tid >> 4, bc = (tid & 15) * 4;
            float4 b = make_float4(0.f, 0.f, 0.f, 0.f);
            if (k0 + bk < Ka){
                const float* bp = B + (long long)(k0 + bk) * ldb + col0 + bc;
                int rem = Nc - (col0 + bc);
                if (rem >= 4) b = *(const float4*)bp;
                else if (rem > 0){ b.x = bp[0]; if (rem > 1) b.y = bp[1]; if (rem > 2) b.z = bp[2]; }
            }
            *(float4*)&Bs[bk][bc] = b;
        }
        __syncthreads();
        #pragma unroll
        for (int k = 0; k < 16; k++){
            float4 a4 = *(const float4*)&As[k][ty * 4];
            float4 b4 = *(const float4*)&Bs[k][tx * 4];
            float av[4] = {a4.x, a4.y, a4.z, a4.w};
            float bv[4] = {b4.x, b4.y, b4.z, b4.w};
            #pragma unroll
            for (int ii = 0; ii < 4; ii++)
                #pragma unroll
                for (int jj = 0; jj < 4; jj++)
                    acc[ii][jj] += av[ii] * bv[jj];
        }
        __syncthreads();
    }
    #pragma unroll
    for (int ii = 0; ii < 4; ii++){
        int r = row0 + ty * 4 + ii;
        if (r >= Mr) continue;
        #pragma unroll
        for (int jj = 0; jj < 4; jj++){
            int c = col0 + tx * 4 + jj;
            if (c < Nc) C[(long long)r * ldc + c] = acc[ii][jj];
        }
    }
}

// ---------------- attention softmax with bias ----------------
__global__ __launch_bounds__(256) void k_softmax(float* __restrict__ attn, const float* __restrict__ bias){
    int n = blockIdx.x, h = blockIdx.y, tid = threadIdx.x;
    __shared__ float rowL[NP1];
    __shared__ float red[256];
    float* rp = attn + (long long)h * NP1 * ATTN_LD + n * ATTN_LD;
    const float* br = bias + (long long)h * NNn + (n - 1) * Nn;
    float lmax = -1e30f;
    for (int m = tid; m < NP1; m += 256){
        float v = rp[m] * SCALING;
        if (n >= 1 && m >= 1) v += br[m - 1];
        rowL[m] = v;
        lmax = fmaxf(lmax, v);
    }
    red[tid] = lmax; __syncthreads();
    for (int s = 128; s > 0; s >>= 1){ if (tid < s) red[tid] = fmaxf(red[tid], red[tid + s]); __syncthreads(); }
    float mx = red[0];
    __syncthreads();
    float lsum = 0.f;
    for (int m = tid; m < NP1; m += 256){
        float e = expf(rowL[m] - mx);
        rowL[m] = e; lsum += e;
    }
    red[tid] = lsum; __syncthreads();
    for (int s = 128; s > 0; s >>= 1){ if (tid < s) red[tid] += red[tid + s]; __syncthreads(); }
    float inv = 1.f / red[0];
    __syncthreads();
    for (int m = tid; m < NP1; m += 256) rp[m] = rowL[m] * inv;
}

__global__ __launch_bounds__(256) void k_ln(const float* __restrict__ xin, const float* __restrict__ z,
                     const float* __restrict__ s, const float* __restrict__ b,
                     float* __restrict__ xout, float* __restrict__ out2){
    int r = blockIdx.x, tid = threadIdx.x;
    __shared__ float red[256];
    float v0 = xin[r * Dd + tid] + z[r * Dd + tid];
    float v1 = xin[r * Dd + tid + 256] + z[r * Dd + tid + 256];
    red[tid] = v0 + v1; __syncthreads();
    for (int st = 128; st > 0; st >>= 1){ if (tid < st) red[tid] += red[tid + st]; __syncthreads(); }
    float mu = red[0] * (1.f / Dd);
    __syncthreads();
    float d0 = v0 - mu, d1 = v1 - mu;
    red[tid] = d0 * d0 + d1 * d1; __syncthreads();
    for (int st = 128; st > 0; st >>= 1){ if (tid < st) red[tid] += red[tid + st]; __syncthreads(); }
    float rstd = rsqrtf(red[0] * (1.f / Dd) + 1e-5f);
    __syncthreads();
    float o0 = d0 * rstd * s[tid] + b[tid];
    float o1 = d1 * rstd * s[tid + 256] + b[tid + 256];
    xout[r * Dd + tid] = o0; xout[r * Dd + tid + 256] = o1;
    if (out2){ out2[r * Dd + tid] = o0; out2[r * Dd + tid + 256] = o1; }
}

__global__ void k_gelu(float* __restrict__ t, int n){
    int i = blockIdx.x * 256 + threadIdx.x;
    if (i < n) t[i] = gelu_f(t[i]);
}

// ---------------- launch ----------------
extern "C" void kernel_launch(void* const* d_in, const int* in_sizes, int n_in,
                              void* d_out, int out_size, void* d_ws, size_t ws_size,
                              hipStream_t stream){
    const float* atoms_x    = (const float*)d_in[0];
    const float* pos        = (const float*)d_in[1];
    const int*   atoms      = (const int*)d_in[2];
    const int*   edge_index = (const int*)d_in[3];
    const int*   edge_attr  = (const int*)d_in[4];
    const int*   spatial_pos= (const int*)d_in[5];
    const int*   edge_input = (const int*)d_in[6];
    const float* atom_tab   = (const float*)d_in[7];
    const float* degree_tab = (const float*)d_in[8];
    const float* w3d        = (const float*)d_in[9];
    const float* spd_tab    = (const float*)d_in[10];
    const float* edge_tab   = (const float*)d_in[11];
    const float* edge_dis   = (const float*)d_in[12];
    const float* means      = (const float*)d_in[13];
    const float* stds       = (const float*)d_in[14];
    const float* gamma_tab  = (const float*)d_in[15];
    const float* beta_tab   = (const float*)d_in[16];
    const float* pW1        = (const float*)d_in[17];
    const float* pW2        = (const float*)d_in[18];
    const float* cls_token  = (const float*)d_in[19];
    const float* Qw         = (const float*)d_in[20];
    const float* Kw         = (const float*)d_in[21];
    const float* Vw         = (const float*)d_in[22];
    const float* Wout       = (const float*)d_in[23];
    const float* F1         = (const float*)d_in[24];
    const float* F2         = (const float*)d_in[25];
    const float* ln1_s      = (const float*)d_in[26];
    const float* ln1_b      = (const float*)d_in[27];
    const float* ln2_s      = (const float*)d_in[28];
    const float* ln2_b      = (const float*)d_in[29];

    char* w = (char*)d_ws;
    float* bias = (float*)w;  w += (size_t)Hh * NNn * 4;        // 16 MB
    float* x    = (float*)w;  w += 1050624;                      // [513,512]
    float* Qa   = (float*)w;  w += 16809984;                     // [513,8192]
    float* Ka_  = (float*)w;  w += 16809984;
    float* Va   = (float*)w;  w += 16809984;
    float* attn = (float*)w;  w += (size_t)Hh * NP1 * ATTN_LD * 4;
    float* o2   = (float*)w;  w += 16809984;
    float* t1   = (float*)w;  w += 1050624;
    float* t2   = (float*)w;  w += 1050624;
    // pre-layer scratch overlaps Qa (all consumed before first GEMM)
    char* sw = (char*)Qa;
    int* sc1        = (int*)sw;   sw += 1048576;
    int* sc2        = (int*)sw;   sw += 1048576;
    int* edge_types = (int*)sw;   sw += 1048576;
    int* degrees    = (int*)sw;   sw += 4096;
    float* dist     = (float*)sw; sw += 1048576;
    float* sumpsi   = (float*)sw; sw += 262144;

    hipMemsetAsync(sc1, 0, 2 * 1048576, stream);
    hipMemsetAsync(sumpsi, 0, 262144, stream);

    k_scatter<<<8, 256, 0, stream>>>(edge_index, sc1, sc2);
    k_combine<<<512, 256, 0, stream>>>(sc1, sc2, edge_attr, edge_types, degrees);
    k_dist<<<1024, 256, 0, stream>>>(pos, dist);
    k_bias_init<<<16384, 256, 0, stream>>>(spatial_pos, edge_input, spd_tab, edge_tab, edge_dis, bias);
    k_psi<<<dim3(8, 512), 256, 0, stream>>>(dist, edge_types, gamma_tab, beta_tab, means, stds, pW1, pW2, sumpsi, bias);
    k_xinit<<<513, 256, 0, stream>>>(atoms_x, atom_tab, degree_tab, w3d, sumpsi, atoms, degrees, cls_token, x);

    for (int l = 0; l < LLl; l++){
        const float* Qwl = Qw + (long long)l * Hh * Dd * Dd;
        const float* Kwl = Kw + (long long)l * Hh * Dd * Dd;
        const float* Vwl = Vw + (long long)l * Hh * Dd * Dd;
        const float* Wol = Wout + (long long)l * Dd * HD;
        const float* F1l = F1 + (long long)l * Dd * Dd;
        const float* F2l = F2 + (long long)l * Dd * Dd;

        k_gemm<1><<<dim3(128, 9), 256, 0, stream>>>(x, Qwl, Qa, NP1, HD, Dd, Dd, Dd, HD, 0, 0, 0);
        k_gemm<1><<<dim3(128, 9), 256, 0, stream>>>(x, Kwl, Ka_, NP1, HD, Dd, Dd, Dd, HD, 0, 0, 0);
        k_gemm<1><<<dim3(128, 9), 256, 0, stream>>>(x, Vwl, Va, NP1, HD, Dd, Dd, Dd, HD, 0, 0, 0);
        // attn logits per head: q_h @ k_h^T
        k_gemm<1><<<dim3(9, 9, 16), 256, 0, stream>>>(Qa, Ka_, attn, NP1, NP1, Dd, HD, HD, ATTN_LD,
                                                      512, 512, (long long)NP1 * ATTN_LD);
        k_softmax<<<dim3(513, 16), 256, 0, stream>>>(attn, bias);
        // o_h = attn_h @ v_h
        k_gemm<0><<<dim3(8, 9, 16), 256, 0, stream>>>(attn, Va, o2, NP1, Dd, NP1, ATTN_LD, HD, HD,
                                                      (long long)NP1 * ATTN_LD, 512, 512);
        k_gemm<1><<<dim3(8, 9), 256, 0, stream>>>(o2, Wol, t1, NP1, Dd, HD, HD, HD, Dd, 0, 0, 0);
        k_ln<<<513, 256, 0, stream>>>(x, t1, ln1_s + l * Dd, ln1_b + l * Dd, x, nullptr);
        k_gemm<1><<<dim3(8, 9), 256, 0, stream>>>(x, F1l, t2, NP1, Dd, Dd, Dd, Dd, Dd, 0, 0, 0);
        k_gelu<<<1026, 256, 0, stream>>>(t2, NP1 * Dd);
        k_gemm<1><<<dim3(8, 9), 256, 0, stream>>>(t2, F2l, t1, NP1, Dd, Dd, Dd, Dd, Dd, 0, 0, 0);
        k_ln<<<513, 256, 0, stream>>>(x, t1, ln2_s + l * Dd, ln2_b + l * Dd, x,
                                      (l == LLl - 1) ? (float*)d_out : nullptr);
    }
}